// Round 3
// baseline (105.816 us; speedup 1.0000x reference)
//
#include <hip/hip_runtime.h>
#include <hip/hip_bf16.h>

#define HIDDEN 128

typedef float floatx4 __attribute__((ext_vector_type(4)));
typedef int   intx4   __attribute__((ext_vector_type(4)));

__device__ __forceinline__ float dot4(floatx4 a, floatx4 b) {
    return a.x * b.x + a.y * b.y + a.z * b.z + a.w * b.w;
}

// Kernel 1: per-node dual projection. 16 lanes per node; each lane loads two
// float4s (256B-contiguous segments per 16-lane group -> fully coalesced),
// dual-dots against W_src/W_dst, 4-step shuffle reduce over 16 lanes.
__global__ void node_proj_kernel(const float* __restrict__ x,
                                 const float* __restrict__ W,
                                 float2* __restrict__ p,
                                 int n_nodes) {
    const int tid  = (int)(blockIdx.x * (unsigned)blockDim.x + threadIdx.x);
    const int lane = tid & 15;
    const int node = tid >> 4;
    if (node >= n_nodes) return;

    const floatx4* xr = (const floatx4*)(x + (size_t)node * HIDDEN);
    const floatx4 xv0 = __builtin_nontemporal_load(xr + lane);        // x[node][lane*4 .. +3]
    const floatx4 xv1 = __builtin_nontemporal_load(xr + 16 + lane);   // x[node][64+lane*4 ..]

    const floatx4* wq = (const floatx4*)W;
    const floatx4 ws0 = wq[lane];
    const floatx4 ws1 = wq[16 + lane];
    const floatx4 wd0 = wq[32 + lane];
    const floatx4 wd1 = wq[48 + lane];

    float ps = dot4(xv0, ws0) + dot4(xv1, ws1);
    float pd = dot4(xv0, wd0) + dot4(xv1, wd1);

    #pragma unroll
    for (int off = 8; off > 0; off >>= 1) {
        ps += __shfl_down(ps, off, 16);
        pd += __shfl_down(pd, off, 16);
    }
    if (lane == 0) p[node] = make_float2(ps, pd);
}

// Kernel 2: per-edge gather-add, 4 edges/thread. p (800 KB) is L2/L3-resident.
// Indices and output are zero-reuse streams -> nontemporal.
__global__ void edge_out_kernel(const int* __restrict__ src,
                                const int* __restrict__ dst,
                                const float2* __restrict__ p,
                                const float* __restrict__ b,
                                float* __restrict__ out,
                                int n_edges) {
    const int base = (int)(blockIdx.x * (unsigned)blockDim.x + threadIdx.x) * 4;
    if (base >= n_edges) return;
    const float bb = b[0];

    if (base + 3 < n_edges) {
        const intx4 s = __builtin_nontemporal_load((const intx4*)(src + base));
        const intx4 d = __builtin_nontemporal_load((const intx4*)(dst + base));
        floatx4 o;
        o.x = p[s.x].x + p[d.x].y + bb;
        o.y = p[s.y].x + p[d.y].y + bb;
        o.z = p[s.z].x + p[d.z].y + bb;
        o.w = p[s.w].x + p[d.w].y + bb;
        __builtin_nontemporal_store(o, (floatx4*)(out + base));
    } else {
        for (int e = base; e < n_edges; ++e) {
            out[e] = p[src[e]].x + p[dst[e]].y + bb;
        }
    }
}

extern "C" void kernel_launch(void* const* d_in, const int* in_sizes, int n_in,
                              void* d_out, int out_size, void* d_ws, size_t ws_size,
                              hipStream_t stream) {
    const float* x   = (const float*)d_in[0];   // (n_nodes, 128) fp32
    const int*   ei  = (const int*)d_in[1];     // (2, n_edges) int32
    const float* W   = (const float*)d_in[2];   // (1, 256) fp32
    const float* b   = (const float*)d_in[3];   // (1,) fp32
    float* out = (float*)d_out;                 // (n_edges,) fp32

    const int n_nodes = in_sizes[0] / HIDDEN;
    const int n_edges = in_sizes[1] / 2;
    const int* src = ei;
    const int* dst = ei + n_edges;

    float2* p = (float2*)d_ws;  // n_nodes * 8 B = 800 KB

    // Kernel 1: 16 lanes/node, 16 nodes per 256-thread block.
    {
        const long long threads = (long long)n_nodes * 16;
        const int grid = (int)((threads + 255) / 256);
        node_proj_kernel<<<grid, 256, 0, stream>>>(x, W, p, n_nodes);
    }

    // Kernel 2: 4 edges/thread.
    {
        const int threads = (n_edges + 3) / 4;
        const int grid = (threads + 255) / 256;
        edge_out_kernel<<<grid, 256, 0, stream>>>(src, dst, p, b, out, n_edges);
    }
}